// Round 2
// baseline (2000.469 us; speedup 1.0000x reference)
//
#include <hip/hip_runtime.h>

#define Dn 512
#define Bn 32
#define Tn 2048
#define BT 65536   // Bn*Tn

typedef unsigned short u16;
typedef __attribute__((ext_vector_type(8))) short short8;   // 8 bf16 = 4 VGPRs (MFMA A/B frag)
typedef __attribute__((ext_vector_type(4))) float floatx4;  // MFMA C/D frag

__device__ __forceinline__ u16 f2bf(float f) {
    unsigned u = __float_as_uint(f);
    unsigned r = (u + 0x7FFFu + ((u >> 16) & 1u)) >> 16;    // RNE
    return (u16)r;
}
__device__ __forceinline__ float bf2f(u16 s) { return __uint_as_float(((unsigned)s) << 16); }

// ---------------------------------------------------------------------------
// 1) x[b][t][d] (f32) -> Xt[d][b*Tn+t] (bf16), LDS 64x64 tile transpose.
// ---------------------------------------------------------------------------
__global__ __launch_bounds__(256) void k_transpose(const float* __restrict__ x,
                                                   u16* __restrict__ Xt) {
    int tt = blockIdx.x;   // t-tile 0..31
    int dt = blockIdx.y;   // d-tile 0..7
    int b  = blockIdx.z;   // 0..31
    __shared__ u16 sT[64][68];  // [d][t], padded
    int tid = threadIdx.x;
    int row = tid >> 4;            // 0..15 (t)
    int c4  = (tid & 15) * 4;      // 0..60 (d)
    const float* src = x + ((long)b * Tn + (long)tt * 64) * Dn + dt * 64;
#pragma unroll
    for (int q = 0; q < 4; q++) {
        int r = row + q * 16;
        floatx4 v = *(const floatx4*)(src + (long)r * Dn + c4);
        sT[c4 + 0][r] = f2bf(v[0]);
        sT[c4 + 1][r] = f2bf(v[1]);
        sT[c4 + 2][r] = f2bf(v[2]);
        sT[c4 + 3][r] = f2bf(v[3]);
    }
    __syncthreads();
    int drow = tid >> 3;           // 0..31 (d)
    int koff = (tid & 7) * 8;      // 0..56 (t)
    long kout = (long)b * Tn + (long)tt * 64 + koff;
#pragma unroll
    for (int p = 0; p < 2; p++) {
        int dr = drow + p * 32;
        u16 tmp[8];
#pragma unroll
        for (int j = 0; j < 8; j++) tmp[j] = sT[dr][koff + j];
        *(short8*)(Xt + (long)(dt * 64 + dr) * BT + kout) = *(short8*)tmp;
    }
}

// ---------------------------------------------------------------------------
// 2) mu[b][d] = (1/T) sum_t Xt[d][b*Tn+t]   (wave per (b,d))
// ---------------------------------------------------------------------------
__global__ __launch_bounds__(256) void k_mu(const u16* __restrict__ Xt,
                                            float* __restrict__ mu) {
    int tid = threadIdx.x;
    int wave = tid >> 6, lane = tid & 63;
    int p = blockIdx.x * 4 + wave;      // 0..16383 == b*512+d
    int b = p >> 9, d = p & 511;
    const u16* src = Xt + (long)d * BT + (long)b * Tn;
    float s = 0.f;
#pragma unroll
    for (int c = 0; c < 4; c++) {
        short8 v = *(const short8*)(src + c * 512 + lane * 8);
#pragma unroll
        for (int j = 0; j < 8; j++) s += bf2f((u16)v[j]);
    }
#pragma unroll
    for (int off = 32; off; off >>= 1) s += __shfl_down(s, off, 64);
    if (lane == 0) mu[p] = s * (1.0f / Tn);
}

// ---------------------------------------------------------------------------
// 3) Gram partials: partial[chunk][d][e] = sum_{k in chunk} Xt[d][k]*Xt[e][k]
//    bf16 MFMA 16x16x32, 128x128 tile, BK=32, 16 K-chunks x 10 sym positions.
// ---------------------------------------------------------------------------
#define LDK 40   // padded LDS row stride (bf16 elems) to spread banks
__global__ __launch_bounds__(256) void k_gram(const u16* __restrict__ Xt,
                                              float* __restrict__ partial) {
    int chunk = blockIdx.x;             // 0..15 (K-chunk of 4096)
    int pos = blockIdx.y;               // 0..9 upper-block-triangle positions
    int di = (pos < 4) ? 0 : (pos < 7) ? 1 : (pos < 9) ? 2 : 3;
    int start = di * 4 - (di * (di - 1)) / 2;   // 0,4,7,9
    int ei = di + (pos - start);
    int d0 = di * 128, e0 = ei * 128;

    __shared__ u16 sA[128 * LDK];
    __shared__ u16 sB[128 * LDK];
    int tid = threadIdx.x;
    int wave = tid >> 6, lane = tid & 63;
    int wm = wave & 1, wn = wave >> 1;  // 2x2 waves over 128x128
    int lrow = tid >> 2;                // 0..63
    int lk = (tid & 3) * 8;             // 0,8,16,24
    const u16* gA = Xt + (long)(d0 + lrow) * BT + (long)chunk * 4096 + lk;
    const u16* gB = Xt + (long)(e0 + lrow) * BT + (long)chunk * 4096 + lk;
    int m = lane & 15, g = lane >> 4;

    floatx4 acc[4][4] = {};
    for (int kk = 0; kk < 4096; kk += 32) {
        short8 a0 = *(const short8*)(gA + kk);
        short8 a1 = *(const short8*)(gA + 64l * BT + kk);
        short8 b0 = *(const short8*)(gB + kk);
        short8 b1 = *(const short8*)(gB + 64l * BT + kk);
        __syncthreads();   // previous iteration's LDS reads done
        *(short8*)(sA + lrow * LDK + lk) = a0;
        *(short8*)(sA + (lrow + 64) * LDK + lk) = a1;
        *(short8*)(sB + lrow * LDK + lk) = b0;
        *(short8*)(sB + (lrow + 64) * LDK + lk) = b1;
        __syncthreads();
        short8 af[4], bf[4];
#pragma unroll
        for (int i = 0; i < 4; i++)
            af[i] = *(const short8*)(sA + (wm * 64 + i * 16 + m) * LDK + g * 8);
#pragma unroll
        for (int j = 0; j < 4; j++)
            bf[j] = *(const short8*)(sB + (wn * 64 + j * 16 + m) * LDK + g * 8);
#pragma unroll
        for (int i = 0; i < 4; i++)
#pragma unroll
            for (int j = 0; j < 4; j++)
                acc[i][j] = __builtin_amdgcn_mfma_f32_16x16x32_bf16(af[i], bf[j], acc[i][j], 0, 0, 0);
    }
    // C/D layout: col = lane&15, row = (lane>>4)*4 + reg   [m89-verified]
    float* P = partial + (long)chunk * (512l * 512);
    int col = lane & 15, rowg = (lane >> 4) * 4;
#pragma unroll
    for (int i = 0; i < 4; i++)
#pragma unroll
        for (int j = 0; j < 4; j++) {
            int rr = d0 + wm * 64 + i * 16 + rowg;
            int cc = e0 + wn * 64 + j * 16 + col;
#pragma unroll
            for (int r = 0; r < 4; r++) P[(long)(rr + r) * 512 + cc] = acc[i][j][r];
        }
}

// ---------------------------------------------------------------------------
// 4) cov[d][e] = (G[d][e] - T * sum_b mu[b,d]*mu[b,e]) / ((T-1)*B)
// ---------------------------------------------------------------------------
__global__ __launch_bounds__(256) void k_assemble(const float* __restrict__ partial,
                                                  const float* __restrict__ mu,
                                                  float* __restrict__ A) {
    int d = blockIdx.y;
    int e = blockIdx.x * 256 + threadIdx.x;
    int bd = d >> 7, be = e >> 7;
    long idx = (bd <= be) ? ((long)d * 512 + e) : ((long)e * 512 + d);  // symmetric mirror
    float s = 0.f;
#pragma unroll
    for (int c = 0; c < 16; c++) s += partial[c * (512l * 512) + idx];
    float msum = 0.f;
#pragma unroll
    for (int b = 0; b < 32; b++) msum += mu[b * 512 + d] * mu[b * 512 + e];
    A[(long)d * 512 + e] = (s - (float)Tn * msum) * (1.0f / ((Tn - 1.0f) * Bn));
}

// ---------------------------------------------------------------------------
// 5a) Cholesky panel: wave0 factors 64x64 diag block in registers (readlane
//     shuffles), then ONE-row-per-thread forward substitution for L21.
//     (Round 1: 2 rows/thread = 128-float arrays spilled to scratch at the
//      128-VGPR cap -> 417us/launch. One row = 64 floats, no spill.)
// ---------------------------------------------------------------------------
__global__ __launch_bounds__(512) void k_chol_panel(float* __restrict__ A, int kb) {
    const int k0 = kb * 64;
    const int rem = 512 - k0 - 64;
    __shared__ float sL[64 * 65];
    __shared__ float sInv[64];
    int tid = threadIdx.x;
    if (tid < 64) {
        int lane = tid;
        float r[64];
        const float* Ar = A + (long)(k0 + lane) * 512 + k0;
#pragma unroll
        for (int j = 0; j < 64; j += 4) {
            floatx4 v = *(const floatx4*)(Ar + j);
            r[j] = v[0]; r[j + 1] = v[1]; r[j + 2] = v[2]; r[j + 3] = v[3];
        }
#pragma unroll
        for (int k = 0; k < 64; k++) {
            float akk = __shfl(r[k], k, 64);
            float sd = sqrtf(akk);
            float inv = 1.0f / sd;
            float lik = (lane == k) ? sd : r[k] * inv;
            r[k] = lik;
            if (lane == k) sInv[k] = inv;
#pragma unroll
            for (int j = k + 1; j < 64; j++) {
                float ljk = __shfl(lik, j, 64);     // compile-time lane -> v_readlane
                r[j] = fmaf(-lik, ljk, r[j]);
            }
        }
#pragma unroll
        for (int j = 0; j < 64; j++) sL[lane * 65 + j] = r[j];
        float* Aw = A + (long)(k0 + lane) * 512 + k0;
#pragma unroll
        for (int j = 0; j < 64; j += 4) {
            floatx4 v; v[0] = r[j]; v[1] = r[j + 1]; v[2] = r[j + 2]; v[3] = r[j + 3];
            *(floatx4*)(Aw + j) = v;
        }
    }
    __syncthreads();
    if (tid < rem) {
        float v[64];                    // 64 floats/thread -> fits in VGPRs
        float* R = A + (long)(k0 + 64 + tid) * 512 + k0;
#pragma unroll
        for (int j = 0; j < 64; j += 4) {
            floatx4 a = *(const floatx4*)(R + j);
            v[j] = a[0]; v[j + 1] = a[1]; v[j + 2] = a[2]; v[j + 3] = a[3];
        }
#pragma unroll
        for (int c = 0; c < 64; c++) {
            float a0 = v[c];
#pragma unroll
            for (int mm = 0; mm < c; mm++) {
                float l = sL[c * 65 + mm];          // wave-uniform broadcast read
                a0 = fmaf(-v[mm], l, a0);
            }
            v[c] = a0 * sInv[c];
        }
#pragma unroll
        for (int j = 0; j < 64; j += 4) {
            floatx4 a; a[0] = v[j]; a[1] = v[j + 1]; a[2] = v[j + 2]; a[3] = v[j + 3];
            *(floatx4*)(R + j) = a;
        }
    }
}

// ---------------------------------------------------------------------------
// 5b) Trailing update: A22 -= L21 * L21^T, one 64x64 tile per block (fp32).
// ---------------------------------------------------------------------------
__global__ __launch_bounds__(256) void k_chol_update(float* __restrict__ A, int kb) {
    int k0 = kb * 64, base = k0 + 64;
    int idx = blockIdx.x, ti = 0;
    while (idx > ti) { idx -= ti + 1; ti++; }
    int tj = idx;
    int r0 = base + ti * 64, c0 = base + tj * 64;
    __shared__ float sI[64][65];
    __shared__ float sJ[64][65];
    int tid = threadIdx.x;
    int row = tid >> 4, c4 = (tid & 15) * 4;
#pragma unroll
    for (int q = 0; q < 4; q++) {
        int rr = row + q * 16;
        *(floatx4*)&sI[rr][c4] = *(const floatx4*)(A + (long)(r0 + rr) * 512 + k0 + c4);
        *(floatx4*)&sJ[rr][c4] = *(const floatx4*)(A + (long)(c0 + rr) * 512 + k0 + c4);
    }
    __syncthreads();
    int ri = (tid >> 4) * 4, cj = (tid & 15) * 4;
    float acc[4][4] = {};
    for (int k = 0; k < 64; k += 4) {
        floatx4 av[4], bv[4];
#pragma unroll
        for (int ii = 0; ii < 4; ii++) av[ii] = *(const floatx4*)&sI[ri + ii][k];
#pragma unroll
        for (int jj = 0; jj < 4; jj++) bv[jj] = *(const floatx4*)&sJ[cj + jj][k];
#pragma unroll
        for (int ii = 0; ii < 4; ii++)
#pragma unroll
            for (int jj = 0; jj < 4; jj++)
#pragma unroll
                for (int q = 0; q < 4; q++)
                    acc[ii][jj] = fmaf(av[ii][q], bv[jj][q], acc[ii][jj]);
    }
#pragma unroll
    for (int ii = 0; ii < 4; ii++) {
        float* dst = A + (long)(r0 + ri + ii) * 512 + c0 + cj;
        floatx4 old = *(const floatx4*)dst;
#pragma unroll
        for (int jj = 0; jj < 4; jj++) old[jj] -= acc[ii][jj];
        *(floatx4*)dst = old;
    }
}

// ---------------------------------------------------------------------------
// 6) out[i][d] = mean[d] + sum_{e<=d} z[i][e] * L[d][e]
// ---------------------------------------------------------------------------
__global__ __launch_bounds__(512) void k_output(const float* __restrict__ z,
                                                const float* __restrict__ A,
                                                const float* __restrict__ mu,
                                                float* __restrict__ out) {
    int i = blockIdx.x, d = threadIdx.x;
    __shared__ float sz[512];
    sz[d] = z[(long)i * 512 + d];
    __syncthreads();
    float mean = 0.f;
#pragma unroll
    for (int b = 0; b < 32; b++) mean += mu[b * 512 + d];
    mean *= (1.0f / 32.0f);
    const float* Lr = A + (long)d * 512;
    float acc = 0.f;
    int dmax = d + 1;
    int e4 = dmax & ~3;
    for (int e = 0; e < e4; e += 4) {
        floatx4 l = *(const floatx4*)(Lr + e);
        acc += l[0] * sz[e] + l[1] * sz[e + 1] + l[2] * sz[e + 2] + l[3] * sz[e + 3];
    }
    for (int e = e4; e < dmax; e++) acc += Lr[e] * sz[e];
    out[(long)i * 512 + d] = mean + acc;
}

// ---------------------------------------------------------------------------
extern "C" void kernel_launch(void* const* d_in, const int* in_sizes, int n_in,
                              void* d_out, int out_size, void* d_ws, size_t ws_size,
                              hipStream_t stream) {
    const float* x = (const float*)d_in[0];
    const float* z = (const float*)d_in[1];
    float* out = (float*)d_out;
    char* ws = (char*)d_ws;
    // ws layout: Xt 67108864B | mu 65536B | partial 16777216B | A 1048576B  (~81 MB)
    u16* Xt = (u16*)ws;
    float* mu = (float*)(ws + 67108864);
    float* partial = (float*)(ws + 67108864 + 65536);
    float* A = (float*)(ws + 67108864 + 65536 + 16777216);

    k_transpose<<<dim3(32, 8, 32), 256, 0, stream>>>(x, Xt);
    k_mu<<<4096, 256, 0, stream>>>(Xt, mu);
    k_gram<<<dim3(16, 10), 256, 0, stream>>>(Xt, partial);
    k_assemble<<<dim3(2, 512), 256, 0, stream>>>(partial, mu, A);
    for (int kb = 0; kb < 8; kb++) {
        k_chol_panel<<<1, 512, 0, stream>>>(A, kb);
        int m = 7 - kb;
        int tiles = m * (m + 1) / 2;
        if (tiles > 0) k_chol_update<<<tiles, 256, 0, stream>>>(A, kb);
    }
    k_output<<<32, 512, 0, stream>>>(z, A, mu, out);
}

// Round 3
// 924.842 us; speedup vs baseline: 2.1630x; 2.1630x over previous
//
#include <hip/hip_runtime.h>

#define Dn 512
#define Bn 32
#define Tn 2048
#define BT 65536   // Bn*Tn

typedef unsigned short u16;
typedef __attribute__((ext_vector_type(8))) short short8;   // 8 bf16 = 4 VGPRs (MFMA A/B frag)
typedef __attribute__((ext_vector_type(4))) float floatx4;  // MFMA C/D frag

__device__ __forceinline__ u16 f2bf(float f) {
    unsigned u = __float_as_uint(f);
    unsigned r = (u + 0x7FFFu + ((u >> 16) & 1u)) >> 16;    // RNE
    return (u16)r;
}
__device__ __forceinline__ float bf2f(u16 s) { return __uint_as_float(((unsigned)s) << 16); }

// ---------------------------------------------------------------------------
// 1) x[b][t][d] (f32) -> Xt[d][b*Tn+t] (bf16), LDS 64x64 tile transpose.
// ---------------------------------------------------------------------------
__global__ __launch_bounds__(256) void k_transpose(const float* __restrict__ x,
                                                   u16* __restrict__ Xt) {
    int tt = blockIdx.x;   // t-tile 0..31
    int dt = blockIdx.y;   // d-tile 0..7
    int b  = blockIdx.z;   // 0..31
    __shared__ u16 sT[64][68];  // [d][t], padded
    int tid = threadIdx.x;
    int row = tid >> 4;            // 0..15 (t)
    int c4  = (tid & 15) * 4;      // 0..60 (d)
    const float* src = x + ((long)b * Tn + (long)tt * 64) * Dn + dt * 64;
#pragma unroll
    for (int q = 0; q < 4; q++) {
        int r = row + q * 16;
        floatx4 v = *(const floatx4*)(src + (long)r * Dn + c4);
        sT[c4 + 0][r] = f2bf(v[0]);
        sT[c4 + 1][r] = f2bf(v[1]);
        sT[c4 + 2][r] = f2bf(v[2]);
        sT[c4 + 3][r] = f2bf(v[3]);
    }
    __syncthreads();
    int drow = tid >> 3;           // 0..31 (d)
    int koff = (tid & 7) * 8;      // 0..56 (t)
    long kout = (long)b * Tn + (long)tt * 64 + koff;
#pragma unroll
    for (int p = 0; p < 2; p++) {
        int dr = drow + p * 32;
        u16 tmp[8];
#pragma unroll
        for (int j = 0; j < 8; j++) tmp[j] = sT[dr][koff + j];
        *(short8*)(Xt + (long)(dt * 64 + dr) * BT + kout) = *(short8*)tmp;
    }
}

// ---------------------------------------------------------------------------
// 2) mu[b][d] = (1/T) sum_t Xt[d][b*Tn+t]   (wave per (b,d))
// ---------------------------------------------------------------------------
__global__ __launch_bounds__(256) void k_mu(const u16* __restrict__ Xt,
                                            float* __restrict__ mu) {
    int tid = threadIdx.x;
    int wave = tid >> 6, lane = tid & 63;
    int p = blockIdx.x * 4 + wave;      // 0..16383 == b*512+d
    int b = p >> 9, d = p & 511;
    const u16* src = Xt + (long)d * BT + (long)b * Tn;
    float s = 0.f;
#pragma unroll
    for (int c = 0; c < 4; c++) {
        short8 v = *(const short8*)(src + c * 512 + lane * 8);
#pragma unroll
        for (int j = 0; j < 8; j++) s += bf2f((u16)v[j]);
    }
#pragma unroll
    for (int off = 32; off; off >>= 1) s += __shfl_down(s, off, 64);
    if (lane == 0) mu[p] = s * (1.0f / Tn);
}

// ---------------------------------------------------------------------------
// 3) Gram partials: partial[chunk][d][e] = sum_{k in chunk} Xt[d][k]*Xt[e][k]
//    bf16 MFMA 16x16x32, 128x128 tile, BK=32, 16 K-chunks x 10 sym positions.
// ---------------------------------------------------------------------------
#define LDK 40   // padded LDS row stride (bf16 elems) to spread banks
__global__ __launch_bounds__(256) void k_gram(const u16* __restrict__ Xt,
                                              float* __restrict__ partial) {
    int chunk = blockIdx.x;             // 0..15 (K-chunk of 4096)
    int pos = blockIdx.y;               // 0..9 upper-block-triangle positions
    int di = (pos < 4) ? 0 : (pos < 7) ? 1 : (pos < 9) ? 2 : 3;
    int start = di * 4 - (di * (di - 1)) / 2;   // 0,4,7,9
    int ei = di + (pos - start);
    int d0 = di * 128, e0 = ei * 128;

    __shared__ u16 sA[128 * LDK];
    __shared__ u16 sB[128 * LDK];
    int tid = threadIdx.x;
    int wave = tid >> 6, lane = tid & 63;
    int wm = wave & 1, wn = wave >> 1;  // 2x2 waves over 128x128
    int lrow = tid >> 2;                // 0..63
    int lk = (tid & 3) * 8;             // 0,8,16,24
    const u16* gA = Xt + (long)(d0 + lrow) * BT + (long)chunk * 4096 + lk;
    const u16* gB = Xt + (long)(e0 + lrow) * BT + (long)chunk * 4096 + lk;
    int m = lane & 15, g = lane >> 4;

    floatx4 acc[4][4] = {};
    for (int kk = 0; kk < 4096; kk += 32) {
        short8 a0 = *(const short8*)(gA + kk);
        short8 a1 = *(const short8*)(gA + 64l * BT + kk);
        short8 b0 = *(const short8*)(gB + kk);
        short8 b1 = *(const short8*)(gB + 64l * BT + kk);
        __syncthreads();   // previous iteration's LDS reads done
        *(short8*)(sA + lrow * LDK + lk) = a0;
        *(short8*)(sA + (lrow + 64) * LDK + lk) = a1;
        *(short8*)(sB + lrow * LDK + lk) = b0;
        *(short8*)(sB + (lrow + 64) * LDK + lk) = b1;
        __syncthreads();
        short8 af[4], bf[4];
#pragma unroll
        for (int i = 0; i < 4; i++)
            af[i] = *(const short8*)(sA + (wm * 64 + i * 16 + m) * LDK + g * 8);
#pragma unroll
        for (int j = 0; j < 4; j++)
            bf[j] = *(const short8*)(sB + (wn * 64 + j * 16 + m) * LDK + g * 8);
#pragma unroll
        for (int i = 0; i < 4; i++)
#pragma unroll
            for (int j = 0; j < 4; j++)
                acc[i][j] = __builtin_amdgcn_mfma_f32_16x16x32_bf16(af[i], bf[j], acc[i][j], 0, 0, 0);
    }
    // C/D layout: col = lane&15, row = (lane>>4)*4 + reg   [m89-verified]
    float* P = partial + (long)chunk * (512l * 512);
    int col = lane & 15, rowg = (lane >> 4) * 4;
#pragma unroll
    for (int i = 0; i < 4; i++)
#pragma unroll
        for (int j = 0; j < 4; j++) {
            int rr = d0 + wm * 64 + i * 16 + rowg;
            int cc = e0 + wn * 64 + j * 16 + col;
#pragma unroll
            for (int r = 0; r < 4; r++) P[(long)(rr + r) * 512 + cc] = acc[i][j][r];
        }
}

// ---------------------------------------------------------------------------
// 4) cov[d][e] = (G[d][e] - T * sum_b mu[b,d]*mu[b,e]) / ((T-1)*B)
// ---------------------------------------------------------------------------
__global__ __launch_bounds__(256) void k_assemble(const float* __restrict__ partial,
                                                  const float* __restrict__ mu,
                                                  float* __restrict__ A) {
    int d = blockIdx.y;
    int e = blockIdx.x * 256 + threadIdx.x;
    int bd = d >> 7, be = e >> 7;
    long idx = (bd <= be) ? ((long)d * 512 + e) : ((long)e * 512 + d);  // symmetric mirror
    float s = 0.f;
#pragma unroll
    for (int c = 0; c < 16; c++) s += partial[c * (512l * 512) + idx];
    float msum = 0.f;
#pragma unroll
    for (int b = 0; b < 32; b++) msum += mu[b * 512 + d] * mu[b * 512 + e];
    A[(long)d * 512 + e] = (s - (float)Tn * msum) * (1.0f / ((Tn - 1.0f) * Bn));
}

// ---------------------------------------------------------------------------
// 5a) Diag factor: ONE wave factors the 64x64 diagonal block in registers.
//     __launch_bounds__(64,1) -> full 512-VGPR budget, no 128-cap spill
//     (rounds 1-2: 512-thread kernel capped at 128 VGPRs -> scratch ->
//      ~500us/launch at VALUBusy 0.006).
//     Writes L11 back and invD[k] = 1/L[k][k].
// ---------------------------------------------------------------------------
__global__ __launch_bounds__(64, 1) void k_chol_diag(float* __restrict__ A,
                                                     float* __restrict__ invD,
                                                     int kb) {
    const int k0 = kb * 64;
    int lane = threadIdx.x;
    float r[64];
    const float* Ar = A + (long)(k0 + lane) * 512 + k0;
#pragma unroll
    for (int j = 0; j < 64; j += 4) {
        floatx4 v = *(const floatx4*)(Ar + j);
        r[j] = v[0]; r[j + 1] = v[1]; r[j + 2] = v[2]; r[j + 3] = v[3];
    }
    float myinv = 0.f;
#pragma unroll
    for (int k = 0; k < 64; k++) {
        float akk = __shfl(r[k], k, 64);
        float sd = sqrtf(akk);
        float inv = 1.0f / sd;
        float lik = (lane == k) ? sd : r[k] * inv;
        r[k] = lik;
        if (lane == k) myinv = inv;
#pragma unroll
        for (int j = k + 1; j < 64; j++) {
            float ljk = __shfl(lik, j, 64);     // compile-time lane -> v_readlane
            r[j] = fmaf(-lik, ljk, r[j]);
        }
    }
    invD[kb * 64 + lane] = myinv;
    float* Aw = A + (long)(k0 + lane) * 512 + k0;
#pragma unroll
    for (int j = 0; j < 64; j += 4) {
        floatx4 v; v[0] = r[j]; v[1] = r[j + 1]; v[2] = r[j + 2]; v[3] = r[j + 3];
        *(floatx4*)(Aw + j) = v;
    }
}

// ---------------------------------------------------------------------------
// 5b) TRSM: L21 = A21 * inv(L11)^T. One wave per 64 rows (parallel across
//     CUs). L11 staged in LDS (stride 68 floats -> 16B-aligned rows for
//     ds_read_b128; reads are wave-uniform broadcasts). Row in registers:
//     v[64] + temps ~ 96 VGPR << 512 cap at __launch_bounds__(64,1).
// ---------------------------------------------------------------------------
__global__ __launch_bounds__(64, 1) void k_chol_trsm(float* __restrict__ A,
                                                     const float* __restrict__ invD,
                                                     int kb) {
    const int k0 = kb * 64;
    int lane = threadIdx.x;
    __shared__ float sL[64 * 68];
    __shared__ float sInv[64];
    const float* Lr = A + (long)(k0 + lane) * 512 + k0;
#pragma unroll
    for (int j = 0; j < 64; j += 4)
        *(floatx4*)(sL + lane * 68 + j) = *(const floatx4*)(Lr + j);
    sInv[lane] = invD[kb * 64 + lane];
    __syncthreads();

    int row = k0 + 64 + blockIdx.x * 64 + lane;
    float v[64];
    float* R = A + (long)row * 512 + k0;
#pragma unroll
    for (int j = 0; j < 64; j += 4) {
        floatx4 a = *(const floatx4*)(R + j);
        v[j] = a[0]; v[j + 1] = a[1]; v[j + 2] = a[2]; v[j + 3] = a[3];
    }
#pragma unroll
    for (int c = 0; c < 64; c++) {
        float a0 = v[c];
#pragma unroll
        for (int mm = 0; mm < c; mm++)
            a0 = fmaf(-v[mm], sL[c * 68 + mm], a0);
        v[c] = a0 * sInv[c];
    }
#pragma unroll
    for (int j = 0; j < 64; j += 4) {
        floatx4 a; a[0] = v[j]; a[1] = v[j + 1]; a[2] = v[j + 2]; a[3] = v[j + 3];
        *(floatx4*)(R + j) = a;
    }
}

// ---------------------------------------------------------------------------
// 5c) Trailing update: A22 -= L21 * L21^T, one 64x64 tile per block (fp32).
// ---------------------------------------------------------------------------
__global__ __launch_bounds__(256) void k_chol_update(float* __restrict__ A, int kb) {
    int k0 = kb * 64, base = k0 + 64;
    int idx = blockIdx.x, ti = 0;
    while (idx > ti) { idx -= ti + 1; ti++; }
    int tj = idx;
    int r0 = base + ti * 64, c0 = base + tj * 64;
    __shared__ float sI[64][65];
    __shared__ float sJ[64][65];
    int tid = threadIdx.x;
    int row = tid >> 4, c4 = (tid & 15) * 4;
#pragma unroll
    for (int q = 0; q < 4; q++) {
        int rr = row + q * 16;
        *(floatx4*)&sI[rr][c4] = *(const floatx4*)(A + (long)(r0 + rr) * 512 + k0 + c4);
        *(floatx4*)&sJ[rr][c4] = *(const floatx4*)(A + (long)(c0 + rr) * 512 + k0 + c4);
    }
    __syncthreads();
    int ri = (tid >> 4) * 4, cj = (tid & 15) * 4;
    float acc[4][4] = {};
    for (int k = 0; k < 64; k += 4) {
        floatx4 av[4], bv[4];
#pragma unroll
        for (int ii = 0; ii < 4; ii++) av[ii] = *(const floatx4*)&sI[ri + ii][k];
#pragma unroll
        for (int jj = 0; jj < 4; jj++) bv[jj] = *(const floatx4*)&sJ[cj + jj][k];
#pragma unroll
        for (int ii = 0; ii < 4; ii++)
#pragma unroll
            for (int jj = 0; jj < 4; jj++)
#pragma unroll
                for (int q = 0; q < 4; q++)
                    acc[ii][jj] = fmaf(av[ii][q], bv[jj][q], acc[ii][jj]);
    }
#pragma unroll
    for (int ii = 0; ii < 4; ii++) {
        float* dst = A + (long)(r0 + ri + ii) * 512 + c0 + cj;
        floatx4 old = *(const floatx4*)dst;
#pragma unroll
        for (int jj = 0; jj < 4; jj++) old[jj] -= acc[ii][jj];
        *(floatx4*)dst = old;
    }
}

// ---------------------------------------------------------------------------
// 6) out[i][d] = mean[d] + sum_{e<=d} z[i][e] * L[d][e]
// ---------------------------------------------------------------------------
__global__ __launch_bounds__(512) void k_output(const float* __restrict__ z,
                                                const float* __restrict__ A,
                                                const float* __restrict__ mu,
                                                float* __restrict__ out) {
    int i = blockIdx.x, d = threadIdx.x;
    __shared__ float sz[512];
    sz[d] = z[(long)i * 512 + d];
    __syncthreads();
    float mean = 0.f;
#pragma unroll
    for (int b = 0; b < 32; b++) mean += mu[b * 512 + d];
    mean *= (1.0f / 32.0f);
    const float* Lr = A + (long)d * 512;
    float acc = 0.f;
    int dmax = d + 1;
    int e4 = dmax & ~3;
    for (int e = 0; e < e4; e += 4) {
        floatx4 l = *(const floatx4*)(Lr + e);
        acc += l[0] * sz[e] + l[1] * sz[e + 1] + l[2] * sz[e + 2] + l[3] * sz[e + 3];
    }
    for (int e = e4; e < dmax; e++) acc += Lr[e] * sz[e];
    out[(long)i * 512 + d] = mean + acc;
}

// ---------------------------------------------------------------------------
extern "C" void kernel_launch(void* const* d_in, const int* in_sizes, int n_in,
                              void* d_out, int out_size, void* d_ws, size_t ws_size,
                              hipStream_t stream) {
    const float* x = (const float*)d_in[0];
    const float* z = (const float*)d_in[1];
    float* out = (float*)d_out;
    char* ws = (char*)d_ws;
    // ws layout: Xt 67108864B | mu 65536B | partial 16777216B | A 1048576B | invD 2048B
    u16* Xt = (u16*)ws;
    float* mu = (float*)(ws + 67108864);
    float* partial = (float*)(ws + 67108864 + 65536);
    float* A = (float*)(ws + 67108864 + 65536 + 16777216);
    float* invD = (float*)(ws + 67108864 + 65536 + 16777216 + 1048576);

    k_transpose<<<dim3(32, 8, 32), 256, 0, stream>>>(x, Xt);
    k_mu<<<4096, 256, 0, stream>>>(Xt, mu);
    k_gram<<<dim3(16, 10), 256, 0, stream>>>(Xt, partial);
    k_assemble<<<dim3(2, 512), 256, 0, stream>>>(partial, mu, A);
    for (int kb = 0; kb < 8; kb++) {
        k_chol_diag<<<1, 64, 0, stream>>>(A, invD, kb);
        int nb = 7 - kb;                 // 64-row row-blocks below the diagonal
        if (nb > 0) k_chol_trsm<<<nb, 64, 0, stream>>>(A, invD, kb);
        int tiles = nb * (nb + 1) / 2;
        if (tiles > 0) k_chol_update<<<tiles, 256, 0, stream>>>(A, kb);
    }
    k_output<<<32, 512, 0, stream>>>(z, A, mu, out);
}